// Round 9
// baseline (295.816 us; speedup 1.0000x reference)
//
#include <hip/hip_runtime.h>
#include <hip/hip_bf16.h>

#define D_MODEL 1024
#define SEQ 2048
#define NH 16
#define HD 64
#define DFF 4096

typedef __attribute__((ext_vector_type(8))) __bf16 bf16x8;
typedef __attribute__((ext_vector_type(4))) float f32x4;

__device__ __forceinline__ unsigned short f2bf(float f) {
    union { float f; unsigned u; } v; v.f = f;
    unsigned r = v.u + 0x7fffu + ((v.u >> 16) & 1u);
    return (unsigned short)(r >> 16);
}
__device__ __forceinline__ unsigned pack2(float a, float b) {
    return (unsigned)f2bf(a) | ((unsigned)f2bf(b) << 16);
}
__device__ __forceinline__ float bf2f(unsigned short u) {
    union { unsigned u; float f; } v; v.u = ((unsigned)u) << 16;
    return v.f;
}
__device__ __forceinline__ bf16x8 ld_frag(const unsigned short* p) {
    union { uint4 u; bf16x8 b; } c;
    c.u = *(const uint4*)p;
    return c.b;
}
__device__ __forceinline__ void load16(const float* p, float* v) {
#pragma unroll
    for (int i = 0; i < 4; i++) {
        float4 f = ((const float4*)p)[i];
        v[4*i+0]=f.x; v[4*i+1]=f.y; v[4*i+2]=f.z; v[4*i+3]=f.w;
    }
}

// async global->LDS DMA, 16B/lane
typedef __attribute__((address_space(3))) unsigned lds_u32;
typedef const __attribute__((address_space(1))) unsigned glob_u32;
__device__ __forceinline__ void gl_lds16(const unsigned short* g, unsigned short* l) {
    __builtin_amdgcn_global_load_lds((glob_u32*)g, (lds_u32*)l, 16, 0, 0);
}

#define MFMA16(a,b,c) __builtin_amdgcn_mfma_f32_16x16x32_bf16(a,b,c,0,0,0)

// ---------------- weight cast + transpose: W[K][N] f32 -> Wt[N][K] bf16 ----------------
__global__ __launch_bounds__(256) void wcast_t(const float* __restrict__ W,
                                               unsigned short* __restrict__ Wt,
                                               int K, int N) {
    __shared__ unsigned short lt[64][72];
    int t = threadIdx.x;
    int nb = blockIdx.x, kb = blockIdx.y;
    int r = t >> 2, c0 = (t & 3) << 4;
    const float* src = W + (size_t)(kb*64 + r) * N + nb*64 + c0;
    float4 f0 = ((const float4*)src)[0];
    float4 f1 = ((const float4*)src)[1];
    float4 f2 = ((const float4*)src)[2];
    float4 f3 = ((const float4*)src)[3];
    unsigned* dst = (unsigned*)&lt[r][c0];
    dst[0]=pack2(f0.x,f0.y); dst[1]=pack2(f0.z,f0.w);
    dst[2]=pack2(f1.x,f1.y); dst[3]=pack2(f1.z,f1.w);
    dst[4]=pack2(f2.x,f2.y); dst[5]=pack2(f2.z,f2.w);
    dst[6]=pack2(f3.x,f3.y); dst[7]=pack2(f3.z,f3.w);
    __syncthreads();
    int n_ = t >> 2, k0 = (t & 3) << 4;
    unsigned obuf[8];
#pragma unroll
    for (int i = 0; i < 8; i++)
        obuf[i] = (unsigned)lt[k0 + 2*i][n_] | ((unsigned)lt[k0 + 2*i + 1][n_] << 16);
    unsigned short* out = Wt + (size_t)(nb*64 + n_) * K + kb*64 + k0;
    ((uint4*)out)[0] = *(uint4*)&obuf[0];
    ((uint4*)out)[1] = *(uint4*)&obuf[4];
}

// ---------------- row LayerNorm: x[SEQ][1024] f32 -> bf16 ----------------
__global__ __launch_bounds__(256) void ln_kernel(const float* __restrict__ x,
                                                 const float* __restrict__ g,
                                                 const float* __restrict__ b,
                                                 unsigned short* __restrict__ out) {
    int row = blockIdx.x, t = threadIdx.x;
    float4 v = ((const float4*)(x + (size_t)row * D_MODEL))[t];
    float s  = v.x + v.y + v.z + v.w;
    float sq = v.x*v.x + v.y*v.y + v.z*v.z + v.w*v.w;
#pragma unroll
    for (int m = 1; m < 64; m <<= 1) { s += __shfl_xor(s, m, 64); sq += __shfl_xor(sq, m, 64); }
    __shared__ float ls[4], lq[4];
    int wave = t >> 6, lane = t & 63;
    if (lane == 0) { ls[wave] = s; lq[wave] = sq; }
    __syncthreads();
    s  = ls[0]+ls[1]+ls[2]+ls[3];
    sq = lq[0]+lq[1]+lq[2]+lq[3];
    float mu  = s * (1.0f / D_MODEL);
    float var = sq * (1.0f / D_MODEL) - mu * mu;
    float rs  = rsqrtf(var + 1e-5f);
    int c = t * 4;
    float y0 = (v.x - mu) * rs * g[c+0] + b[c+0];
    float y1 = (v.y - mu) * rs * g[c+1] + b[c+1];
    float y2 = (v.z - mu) * rs * g[c+2] + b[c+2];
    float y3 = (v.w - mu) * rs * g[c+3] + b[c+3];
    unsigned* o = (unsigned*)(out + (size_t)row * D_MODEL + c);
    o[0] = pack2(y0, y1); o[1] = pack2(y2, y3);
}

// ---------------- reduce: out = res + bias[col] + sum(NP bf16 partial slices) ----------------
template<int NP>
__device__ __forceinline__ void reduce_body(const float* __restrict__ res,
                                            const float* __restrict__ bias,
                                            const unsigned short* __restrict__ parts,
                                            float* __restrict__ out,
                                            int MN, int Ndiv4) {
    int i = blockIdx.x * 256 + threadIdx.x;
    float4 r = ((const float4*)res)[i];
    float4 b = ((const float4*)bias)[i & (Ndiv4 - 1)];
    r.x += b.x; r.y += b.y; r.z += b.z; r.w += b.w;
#pragma unroll
    for (int p = 0; p < NP; p++) {
        ushort4 u = ((const ushort4*)(parts + (size_t)p * MN))[i];
        r.x += bf2f(u.x); r.y += bf2f(u.y); r.z += bf2f(u.z); r.w += bf2f(u.w);
    }
    ((float4*)out)[i] = r;
}
__global__ __launch_bounds__(256) void reduce_op(const float* res, const float* bias,
                                                 const unsigned short* parts, float* out,
                                                 int MN, int Ndiv4) {
    reduce_body<2>(res, bias, parts, out, MN, Ndiv4);
}
__global__ __launch_bounds__(256) void reduce_ff2(const float* res, const float* bias,
                                                  const unsigned short* parts, float* out,
                                                  int MN, int Ndiv4) {
    reduce_body<4>(res, bias, parts, out, MN, Ndiv4);
}

// ---------------- GEMM-BT v5: BK=64 DMA dbuf + PANEL-RASTERIZED 1D grid ----------------
// blockIdx.x is flat; mapping groups panels of 8 bn across ALL bm:
//   panel working set = 8 weight tiles (1MB @K=1024) + A matrix slabs -> fits aggregate L2,
//   so weights are fetched ~once instead of once per bm-phase (R3 FETCH showed ~3x over-fetch).
template<int TM, int TN, int SPLITK, int GELU, int RES, int OUTBF, int PART>
__device__ __forceinline__ void gemm_body(const unsigned short* __restrict__ A,
                                          const unsigned short* __restrict__ Bt,
                                          const float* __restrict__ bias,
                                          const float* __restrict__ res,
                                          void* __restrict__ C,
                                          int M, int N, int K) {
    constexpr int AI = TM / 32;
    constexpr int BI = TN / 32;
    constexpr int MI = TM / 32;
    constexpr int NI = TN / 32;
    constexpr int HALF = (TM + TN) * 64;
    __shared__ unsigned short smem[2 * HALF];
    int t = threadIdx.x;
    // panel swizzle: GY = M/TM bm-tiles, panels of 8 bn
    int GY = M / TM;
    int flat = blockIdx.x;
    int pwgy = 8 * GY;
    int panel = flat / pwgy;
    int rem = flat - panel * pwgy;
    int bm = rem >> 3;
    int bn = panel * 8 + (rem & 7);
    int kz = (SPLITK > 1) ? blockIdx.z : 0;
    int KS = K / SPLITK;
    int K0 = kz * KS;
    int wave = t >> 6, lane = t & 63;
    int quad = lane >> 4, lr = lane & 15;

    const unsigned short* pa[AI];
    int aoff[AI];
#pragma unroll
    for (int i = 0; i < AI; i++) {
        int rl = wave*(TM/4) + i*8 + (lane >> 3);
        int ss = (lane & 7) ^ (rl & 7);
        pa[i] = A + (size_t)(bm*TM + rl) * K + K0 + ss*8;
        aoff[i] = (wave*(TM/4) + i*8) * 64;
    }
    const unsigned short* pb[BI];
    int boff[BI];
#pragma unroll
    for (int i = 0; i < BI; i++) {
        int rl = wave*(TN/4) + i*8 + (lane >> 3);
        int ss = (lane & 7) ^ (rl & 7);
        pb[i] = Bt + (size_t)(bn*TN + rl) * K + K0 + ss*8;
        boff[i] = TM*64 + (wave*(TN/4) + i*8) * 64;
    }

    int wr = (wave >> 1) * (TM/2), wc = (wave & 1) * (TN/2);
    int foA[2][MI], foB[2][NI];
#pragma unroll
    for (int i = 0; i < MI; i++) {
        int row = wr + i*16 + lr;
        foA[0][i] = row*64 + ((quad     ^ (row & 7)))*8;
        foA[1][i] = row*64 + (((quad+4) ^ (row & 7)))*8;
    }
#pragma unroll
    for (int j = 0; j < NI; j++) {
        int row = wc + j*16 + lr;
        foB[0][j] = TM*64 + row*64 + ((quad     ^ (row & 7)))*8;
        foB[1][j] = TM*64 + row*64 + (((quad+4) ^ (row & 7)))*8;
    }

    f32x4 z = {0.f, 0.f, 0.f, 0.f};
    f32x4 acc[MI][NI];
#pragma unroll
    for (int i = 0; i < MI; i++)
#pragma unroll
        for (int j = 0; j < NI; j++) acc[i][j] = z;

#pragma unroll
    for (int i = 0; i < AI; i++) gl_lds16(pa[i], smem + aoff[i]);
#pragma unroll
    for (int i = 0; i < BI; i++) gl_lds16(pb[i], smem + boff[i]);

    int bo = 0;
    for (int kk = 0; kk < KS; kk += 64) {
        __syncthreads();
        if (kk + 64 < KS) {
            int nb = bo ^ HALF;
#pragma unroll
            for (int i = 0; i < AI; i++) gl_lds16(pa[i] + kk + 64, smem + nb + aoff[i]);
#pragma unroll
            for (int i = 0; i < BI; i++) gl_lds16(pb[i] + kk + 64, smem + nb + boff[i]);
        }
#pragma unroll
        for (int h = 0; h < 2; h++) {
            bf16x8 af[MI], bfr[NI];
#pragma unroll
            for (int i = 0; i < MI; i++) af[i]  = ld_frag(smem + bo + foA[h][i]);
#pragma unroll
            for (int j = 0; j < NI; j++) bfr[j] = ld_frag(smem + bo + foB[h][j]);
#pragma unroll
            for (int i = 0; i < MI; i++)
#pragma unroll
                for (int j = 0; j < NI; j++)
                    acc[i][j] = MFMA16(af[i], bfr[j], acc[i][j]);
        }
        bo ^= HALF;
    }

    if (PART) {
        unsigned short* P = (unsigned short*)C + (size_t)kz * M * N;
#pragma unroll
        for (int i = 0; i < MI; i++)
#pragma unroll
            for (int j = 0; j < NI; j++) {
                int row0 = bm*TM + wr + i*16 + quad*4;
                int col  = bn*TN + wc + j*16 + lr;
#pragma unroll
                for (int r = 0; r < 4; r++)
                    P[(size_t)(row0 + r) * N + col] = f2bf(acc[i][j][r]);
            }
    } else {
#pragma unroll
        for (int i = 0; i < MI; i++)
#pragma unroll
            for (int j = 0; j < NI; j++) {
                int row0 = bm*TM + wr + i*16 + quad*4;
                int col  = bn*TN + wc + j*16 + lr;
                float bv = bias[col];
#pragma unroll
                for (int r = 0; r < 4; r++) {
                    float v = acc[i][j][r] + bv;
                    if (RES)  v += res[(size_t)(row0 + r) * N + col];
                    if (GELU) v = 0.5f * v * (1.0f + erff(v * 0.70710678118654752f));
                    if (OUTBF) ((unsigned short*)C)[(size_t)(row0 + r) * N + col] = f2bf(v);
                    else       ((float*)C)[(size_t)(row0 + r) * N + col] = v;
                }
            }
    }
}

// distinct names per gemm for rocprof visibility
__global__ __launch_bounds__(256) void k_gemm_qkv(const unsigned short* A, const unsigned short* Bt,
                                                  const float* bias, float* C, int M, int N, int K) {
    gemm_body<128,64,1,0,0,0,0>(A, Bt, bias, nullptr, C, M, N, K);
}
__global__ __launch_bounds__(256) void k_gemm_op(const unsigned short* A, const unsigned short* Bt,
                                                 unsigned short* C, int M, int N, int K) {
    gemm_body<128,64,2,0,0,0,1>(A, Bt, nullptr, nullptr, C, M, N, K);
}
__global__ __launch_bounds__(256) void k_gemm_ff1(const unsigned short* A, const unsigned short* Bt,
                                                  const float* bias, unsigned short* C, int M, int N, int K) {
    gemm_body<128,64,1,1,0,1,0>(A, Bt, bias, nullptr, C, M, N, K);
}
__global__ __launch_bounds__(256) void k_gemm_ff2(const unsigned short* A, const unsigned short* Bt,
                                                  unsigned short* C, int M, int N, int K) {
    gemm_body<128,64,4,0,0,0,1>(A, Bt, nullptr, nullptr, C, M, N, K);
}

// ---------------- QKV postprocess (R3-proven): normalize q,k; qn,kn [h][l][d], vt [h][d][l] ----------------
__global__ __launch_bounds__(256) void qkv_post(const float* __restrict__ qkv,
                                                unsigned short* __restrict__ qn,
                                                unsigned short* __restrict__ kn,
                                                unsigned short* __restrict__ vt) {
    __shared__ unsigned short lv[64][72];
    int h = blockIdx.x, lb = blockIdx.y;
    int t = threadIdx.x;
    int lloc = t >> 2, seg = (t & 3) << 4;
    int lg = lb*64 + lloc;
    const float* row = qkv + (size_t)lg * 3072;
    float vq[16], vk[16], vv[16];
    load16(row + h*64 + seg, vq);
    load16(row + 1024 + h*64 + seg, vk);
    load16(row + 2048 + h*64 + seg, vv);
    float sq = 0.f, sk = 0.f;
#pragma unroll
    for (int i = 0; i < 16; i++) { sq += vq[i]*vq[i]; sk += vk[i]*vk[i]; }
    sq += __shfl_xor(sq, 1, 64); sq += __shfl_xor(sq, 2, 64);
    sk += __shfl_xor(sk, 1, 64); sk += __shfl_xor(sk, 2, 64);
    float scq = 0.125f / fmaxf(sqrtf(sq), 1e-12f);   // fold 1/sqrt(d) into q
    float sck = 1.0f   / fmaxf(sqrtf(sk), 1e-12f);
    unsigned* oq = (unsigned*)(qn + ((size_t)h*SEQ + lg)*HD + seg);
    unsigned* ok = (unsigned*)(kn + ((size_t)h*SEQ + lg)*HD + seg);
#pragma unroll
    for (int i = 0; i < 8; i++) {
        oq[i] = pack2(vq[2*i]*scq, vq[2*i+1]*scq);
        ok[i] = pack2(vk[2*i]*sck, vk[2*i+1]*sck);
    }
    unsigned* lvp = (unsigned*)&lv[lloc][seg];
#pragma unroll
    for (int i = 0; i < 8; i++) lvp[i] = pack2(vv[2*i], vv[2*i+1]);
    __syncthreads();
    int dloc = t >> 2, l0 = (t & 3) << 4;
    unsigned obuf[8];
#pragma unroll
    for (int i = 0; i < 8; i++)
        obuf[i] = (unsigned)lv[l0 + 2*i][dloc] | ((unsigned)lv[l0 + 2*i + 1][dloc] << 16);
    unsigned short* ov = vt + ((size_t)h*HD + dloc)*SEQ + lb*64 + l0;
    ((uint4*)ov)[0] = *(uint4*)&obuf[0];
    ((uint4*)ov)[1] = *(uint4*)&obuf[4];
}

// ---------------- attention v5 (unchanged from R8): key-split KSPLIT=2 ----------------
#define KSPLIT 2
#define KTILES (SEQ / 64 / KSPLIT)   // 16
__global__ __launch_bounds__(256) void attn_kernel(const unsigned short* __restrict__ qn,
                                                   const unsigned short* __restrict__ kn,
                                                   const unsigned short* __restrict__ vt,
                                                   const float* __restrict__ lcc,
                                                   float* __restrict__ num_ws,
                                                   float* __restrict__ den_ws) {
    __shared__ unsigned short lQ[64][72];
    __shared__ unsigned short lK[64][72];
    __shared__ unsigned short lV[64][72];   // [d][key]
    __shared__ unsigned short lP[64][72];   // [q_local][key]
    __shared__ float lL[SEQ / KSPLIT];
    int h = blockIdx.x, qb = blockIdx.y, kz = blockIdx.z;
    int t = threadIdx.x;
    int rl = t >> 2, c0 = (t & 3) << 4;
    const unsigned short* pq = qn + ((size_t)h*SEQ + qb*64 + rl)*HD + c0;
    *(uint4*)&lQ[rl][c0]     = ((const uint4*)pq)[0];
    *(uint4*)&lQ[rl][c0 + 8] = ((const uint4*)pq)[1];
    for (int i = t; i < SEQ/KSPLIT; i += 256) lL[i] = 0.05f * lcc[kz*(SEQ/KSPLIT) + i];
    __syncthreads();
    int wave = t >> 6, lane = t & 63, quad = lane >> 4, lr = lane & 15;
    float lqv[4];
#pragma unroll
    for (int r = 0; r < 4; r++) lqv[r] = 0.05f * lcc[qb*64 + wave*16 + quad*4 + r];
    bf16x8 aq0 = ld_frag(&lQ[wave*16 + lr][quad*8]);
    bf16x8 aq1 = ld_frag(&lQ[wave*16 + lr][32 + quad*8]);
    f32x4 z = {0.f, 0.f, 0.f, 0.f};
    f32x4 oacc[4]; oacc[0]=z; oacc[1]=z; oacc[2]=z; oacc[3]=z;
    float den[4] = {0.f, 0.f, 0.f, 0.f};

    const unsigned short* kn0 = kn + (size_t)h*SEQ*HD + (size_t)kz*(SEQ/KSPLIT)*HD;
    const unsigned short* vt0 = vt + (size_t)h*HD*SEQ + kz*(SEQ/KSPLIT);

    for (int kb = 0; kb < KTILES; kb++) {
        __syncthreads();
        const unsigned short* pk = kn0 + (size_t)(kb*64 + rl)*HD + c0;
        uint4 k0v = ((const uint4*)pk)[0], k1v = ((const uint4*)pk)[1];
        const unsigned short* pv = vt0 + (size_t)rl*SEQ + kb*64 + c0;
        uint4 v0v = ((const uint4*)pv)[0], v1v = ((const uint4*)pv)[1];
        *(uint4*)&lK[rl][c0]     = k0v; *(uint4*)&lK[rl][c0 + 8] = k1v;
        *(uint4*)&lV[rl][c0]     = v0v; *(uint4*)&lV[rl][c0 + 8] = v1v;
        __syncthreads();
#pragma unroll
        for (int j = 0; j < 4; j++) {
            bf16x8 b0 = ld_frag(&lK[j*16 + lr][quad*8]);
            bf16x8 b1 = ld_frag(&lK[j*16 + lr][32 + quad*8]);
            f32x4 s = z;
            s = MFMA16(aq0, b0, s);
            s = MFMA16(aq1, b1, s);
            float lm = lL[kb*64 + j*16 + lr];
#pragma unroll
            for (int r = 0; r < 4; r++) {
                float sv = s[r] + lqv[r] + lm;
                sv = fminf(fmaxf(sv, -10.f), 10.f);
                float p = __expf(sv);
                den[r] += p;
                lP[wave*16 + quad*4 + r][j*16 + lr] = f2bf(p);
            }
        }
        bf16x8 ap0 = ld_frag(&lP[wave*16 + lr][quad*8]);
        bf16x8 ap1 = ld_frag(&lP[wave*16 + lr][32 + quad*8]);
#pragma unroll
        for (int j2 = 0; j2 < 4; j2++) {
            bf16x8 b0 = ld_frag(&lV[j2*16 + lr][quad*8]);
            bf16x8 b1 = ld_frag(&lV[j2*16 + lr][32 + quad*8]);
            oacc[j2] = MFMA16(ap0, b0, oacc[j2]);
            oacc[j2] = MFMA16(ap1, b1, oacc[j2]);
        }
    }
#pragma unroll
    for (int r = 0; r < 4; r++)
#pragma unroll
        for (int m = 1; m < 16; m <<= 1) den[r] += __shfl_xor(den[r], m, 64);

    float* nump = num_ws + (((size_t)(h*32 + qb)) * KSPLIT + kz) * 4096;
#pragma unroll
    for (int j2 = 0; j2 < 4; j2++)
#pragma unroll
        for (int r = 0; r < 4; r++)
            nump[(wave*16 + quad*4 + r) * 64 + j2*16 + lr] = oacc[j2][r];
    if (lr == 0) {
        float* denp = den_ws + (((size_t)(h*32 + qb)) * KSPLIT + kz) * 64;
#pragma unroll
        for (int r = 0; r < 4; r++) denp[wave*16 + quad*4 + r] = den[r];
    }
}

// combine: out[qb*64+row][h*64+col] = sum_kz num / sum_kz den
__global__ __launch_bounds__(256) void attn_comb(const float* __restrict__ num_ws,
                                                 const float* __restrict__ den_ws,
                                                 unsigned short* __restrict__ attn) {
    int hq = blockIdx.x;          // h*32+qb
    int h = hq >> 5, qb = hq & 31;
    int t = threadIdx.x;
    int row = t >> 2, col0 = (t & 3) << 4;
    const float* n0 = num_ws + ((size_t)hq * KSPLIT) * 4096 + row*64 + col0;
    const float* n1 = n0 + 4096;
    float d = den_ws[(size_t)hq * KSPLIT * 64 + row] + den_ws[((size_t)hq * KSPLIT + 1) * 64 + row];
    float inv = 1.0f / d;
    unsigned ob[8];
#pragma unroll
    for (int i = 0; i < 4; i++) {
        float4 a = ((const float4*)n0)[i];
        float4 b = ((const float4*)n1)[i];
        ob[2*i]   = pack2((a.x + b.x) * inv, (a.y + b.y) * inv);
        ob[2*i+1] = pack2((a.z + b.z) * inv, (a.w + b.w) * inv);
    }
    unsigned short* op = attn + (size_t)(qb*64 + row) * D_MODEL + h*64 + col0;
    ((uint4*)op)[0] = *(uint4*)&ob[0];
    ((uint4*)op)[1] = *(uint4*)&ob[4];
}

// ---------------- host orchestration ----------------
extern "C" void kernel_launch(void* const* d_in, const int* in_sizes, int n_in,
                              void* d_out, int out_size, void* d_ws, size_t ws_size,
                              hipStream_t stream) {
    const float* x      = (const float*)d_in[0];
    const float* lcc    = (const float*)d_in[1];
    const float* w_qkv  = (const float*)d_in[2];
    const float* b_qkv  = (const float*)d_in[3];
    const float* w_out  = (const float*)d_in[4];
    const float* b_out  = (const float*)d_in[5];
    const float* ln1_g  = (const float*)d_in[6];
    const float* ln1_b  = (const float*)d_in[7];
    const float* ln2_g  = (const float*)d_in[8];
    const float* ln2_b  = (const float*)d_in[9];
    const float* w_ff1  = (const float*)d_in[10];
    const float* b_ff1  = (const float*)d_in[11];
    const float* w_ff2  = (const float*)d_in[12];
    const float* b_ff2  = (const float*)d_in[13];

    char* ws = (char*)d_ws;
    unsigned short* wtq  = (unsigned short*)(ws);                    // 3072x1024 bf16 = 6291456
    unsigned short* wto  = (unsigned short*)(ws + 6291456);          // -> 8388608
    unsigned short* wtf1 = (unsigned short*)(ws + 8388608);          // -> 16777216
    unsigned short* wtf2 = (unsigned short*)(ws + 16777216);         // -> 25165824
    unsigned short* xn   = (unsigned short*)(ws + 25165824);         // -> 29360128
    float*          qkvb = (float*)(ws + 29360128);                  // 2048x3072 f32 -> 54525952
    float*          x1   = (float*)(ws + 29360128);                  // alias (qkvb dead after qkv_post)
    float*          numw = (float*)(ws + 29360128);                  // alias: 16.8MB attn num partials
    float*          denw = (float*)(ws + 46137344);                  // 256KB attn den partials
    unsigned short* hbuf = (unsigned short*)(ws + 37748736);         // 2048x4096 bf16 -> 54525952
    unsigned short* pOP  = (unsigned short*)(ws + 37748736);         // alias: 2 bf16 slices
    unsigned short* qnb  = (unsigned short*)(ws + 54525952);         // -> 58720256
    unsigned short* knb  = (unsigned short*)(ws + 58720256);         // -> 62914560
    unsigned short* vtb  = (unsigned short*)(ws + 62914560);         // -> 67108864
    unsigned short* pFF2 = (unsigned short*)(ws);                    // alias (weights dead)
    unsigned short* attnb = xn;                                      // alias (xn dead after QKV gemm)
    unsigned short* x2n  = qnb;                                      // alias (qn dead after attention)
    float* outp = (float*)d_out;

    // Ordering hazards (all sequential on one stream -> safe): numw aliases qkvb/x1; attn
    // partials written after qkv_post consumed qkvb, consumed by attn_comb before reduce_op
    // writes x1. pOP overlaps numw tail: OP gemm runs after attn_comb.

    wcast_t<<<dim3(48, 16), 256, 0, stream>>>(w_qkv, wtq, 1024, 3072);
    wcast_t<<<dim3(16, 16), 256, 0, stream>>>(w_out, wto, 1024, 1024);
    wcast_t<<<dim3(64, 16), 256, 0, stream>>>(w_ff1, wtf1, 1024, 4096);
    wcast_t<<<dim3(16, 64), 256, 0, stream>>>(w_ff2, wtf2, 4096, 1024);
    ln_kernel<<<SEQ, 256, 0, stream>>>(x, ln1_g, ln1_b, xn);
    k_gemm_qkv<<<dim3(48*16), 256, 0, stream>>>(xn, wtq, b_qkv, qkvb, SEQ, 3072, 1024);
    qkv_post<<<dim3(16, 32), 256, 0, stream>>>(qkvb, qnb, knb, vtb);
    attn_kernel<<<dim3(16, 32, KSPLIT), 256, 0, stream>>>(qnb, knb, vtb, lcc, numw, denw);
    attn_comb<<<512, 256, 0, stream>>>(numw, denw, attnb);
    k_gemm_op<<<dim3(16*16, 1, 2), 256, 0, stream>>>(attnb, wto, pOP, SEQ, 1024, 1024);
    reduce_op<<<SEQ*D_MODEL/1024, 256, 0, stream>>>(x, b_out, pOP, x1, SEQ*D_MODEL, D_MODEL/4);
    ln_kernel<<<SEQ, 256, 0, stream>>>(x1, ln2_g, ln2_b, x2n);
    k_gemm_ff1<<<dim3(64*16), 256, 0, stream>>>(x2n, wtf1, b_ff1, hbuf, SEQ, 4096, 1024);
    k_gemm_ff2<<<dim3(16*16, 1, 4), 256, 0, stream>>>(hbuf, wtf2, pFF2, SEQ, 1024, 4096);
    reduce_ff2<<<SEQ*D_MODEL/1024, 256, 0, stream>>>(x1, b_ff2, pFF2, outp, SEQ*D_MODEL, D_MODEL/4);
}

// Round 10
// 273.426 us; speedup vs baseline: 1.0819x; 1.0819x over previous
//
#include <hip/hip_runtime.h>
#include <hip/hip_bf16.h>

#define D_MODEL 1024
#define SEQ 2048
#define NH 16
#define HD 64
#define DFF 4096

typedef __attribute__((ext_vector_type(8))) __bf16 bf16x8;
typedef __attribute__((ext_vector_type(4))) float f32x4;

__device__ __forceinline__ unsigned short f2bf(float f) {
    union { float f; unsigned u; } v; v.f = f;
    unsigned r = v.u + 0x7fffu + ((v.u >> 16) & 1u);
    return (unsigned short)(r >> 16);
}
__device__ __forceinline__ unsigned pack2(float a, float b) {
    return (unsigned)f2bf(a) | ((unsigned)f2bf(b) << 16);
}
__device__ __forceinline__ float bf2f(unsigned short u) {
    union { unsigned u; float f; } v; v.u = ((unsigned)u) << 16;
    return v.f;
}
__device__ __forceinline__ bf16x8 ld_frag(const unsigned short* p) {
    union { uint4 u; bf16x8 b; } c;
    c.u = *(const uint4*)p;
    return c.b;
}

// async global->LDS DMA, 16B/lane
typedef __attribute__((address_space(3))) unsigned lds_u32;
typedef const __attribute__((address_space(1))) unsigned glob_u32;
__device__ __forceinline__ void gl_lds16(const unsigned short* g, unsigned short* l) {
    __builtin_amdgcn_global_load_lds((glob_u32*)g, (lds_u32*)l, 16, 0, 0);
}

#define MFMA16(a,b,c) __builtin_amdgcn_mfma_f32_16x16x32_bf16(a,b,c,0,0,0)

// ---------------- fused weight cast+transpose: all 4 weights in one launch ----------------
__global__ __launch_bounds__(256) void wcast_all(const float* __restrict__ wq, const float* __restrict__ wo,
                                                 const float* __restrict__ wf1, const float* __restrict__ wf2,
                                                 unsigned short* __restrict__ oq, unsigned short* __restrict__ oo,
                                                 unsigned short* __restrict__ of1, unsigned short* __restrict__ of2) {
    __shared__ unsigned short lt[64][72];
    int id = blockIdx.x;
    const float* W; unsigned short* O; int K, N, nb, kb;
    if (id < 768)       { W = wq;  O = oq;  K = 1024; N = 3072; nb = id % 48; kb = id / 48; }
    else if (id < 1024) { id -= 768;  W = wo;  O = oo;  K = 1024; N = 1024; nb = id & 15; kb = id >> 4; }
    else if (id < 2048) { id -= 1024; W = wf1; O = of1; K = 1024; N = 4096; nb = id & 63; kb = id >> 6; }
    else                { id -= 2048; W = wf2; O = of2; K = 4096; N = 1024; nb = id & 15; kb = id >> 4; }
    int t = threadIdx.x;
    int r = t >> 2, c0 = (t & 3) << 4;
    const float* src = W + (size_t)(kb*64 + r) * N + nb*64 + c0;
    float4 f0 = ((const float4*)src)[0];
    float4 f1 = ((const float4*)src)[1];
    float4 f2 = ((const float4*)src)[2];
    float4 f3 = ((const float4*)src)[3];
    unsigned* dst = (unsigned*)&lt[r][c0];
    dst[0]=pack2(f0.x,f0.y); dst[1]=pack2(f0.z,f0.w);
    dst[2]=pack2(f1.x,f1.y); dst[3]=pack2(f1.z,f1.w);
    dst[4]=pack2(f2.x,f2.y); dst[5]=pack2(f2.z,f2.w);
    dst[6]=pack2(f3.x,f3.y); dst[7]=pack2(f3.z,f3.w);
    __syncthreads();
    int n_ = t >> 2, k0 = (t & 3) << 4;
    unsigned obuf[8];
#pragma unroll
    for (int i = 0; i < 8; i++)
        obuf[i] = (unsigned)lt[k0 + 2*i][n_] | ((unsigned)lt[k0 + 2*i + 1][n_] << 16);
    unsigned short* out = O + (size_t)(nb*64 + n_) * K + kb*64 + k0;
    ((uint4*)out)[0] = *(uint4*)&obuf[0];
    ((uint4*)out)[1] = *(uint4*)&obuf[4];
}

// ---------------- row LayerNorm (LN1): x[SEQ][1024] f32 -> bf16 ----------------
__global__ __launch_bounds__(256) void ln_kernel(const float* __restrict__ x,
                                                 const float* __restrict__ g,
                                                 const float* __restrict__ b,
                                                 unsigned short* __restrict__ out) {
    int row = blockIdx.x, t = threadIdx.x;
    float4 v = ((const float4*)(x + (size_t)row * D_MODEL))[t];
    float s  = v.x + v.y + v.z + v.w;
    float sq = v.x*v.x + v.y*v.y + v.z*v.z + v.w*v.w;
#pragma unroll
    for (int m = 1; m < 64; m <<= 1) { s += __shfl_xor(s, m, 64); sq += __shfl_xor(sq, m, 64); }
    __shared__ float ls[4], lq[4];
    int wave = t >> 6, lane = t & 63;
    if (lane == 0) { ls[wave] = s; lq[wave] = sq; }
    __syncthreads();
    s  = ls[0]+ls[1]+ls[2]+ls[3];
    sq = lq[0]+lq[1]+lq[2]+lq[3];
    float mu  = s * (1.0f / D_MODEL);
    float var = sq * (1.0f / D_MODEL) - mu * mu;
    float rs  = rsqrtf(var + 1e-5f);
    int c = t * 4;
    float y0 = (v.x - mu) * rs * g[c+0] + b[c+0];
    float y1 = (v.y - mu) * rs * g[c+1] + b[c+1];
    float y2 = (v.z - mu) * rs * g[c+2] + b[c+2];
    float y3 = (v.w - mu) * rs * g[c+3] + b[c+3];
    unsigned* o = (unsigned*)(out + (size_t)row * D_MODEL + c);
    o[0] = pack2(y0, y1); o[1] = pack2(y2, y3);
}

// ---------------- fused residual-reduce + LN2: x1 = x + b_out + p0 + p1; x2n = LN(x1) ----------------
__global__ __launch_bounds__(256) void reduce_ln(const float* __restrict__ x,
                                                 const float* __restrict__ bout,
                                                 const unsigned short* __restrict__ parts,
                                                 const float* __restrict__ g,
                                                 const float* __restrict__ b,
                                                 float* __restrict__ x1,
                                                 unsigned short* __restrict__ x2n) {
    int row = blockIdx.x, t = threadIdx.x;
    int i = row * 256 + t;
    float4 v = ((const float4*)x)[i];
    float4 bb = ((const float4*)bout)[t];
    v.x += bb.x; v.y += bb.y; v.z += bb.z; v.w += bb.w;
    ushort4 u0 = ((const ushort4*)parts)[i];
    ushort4 u1 = ((const ushort4*)(parts + (size_t)SEQ*D_MODEL))[i];
    v.x += bf2f(u0.x) + bf2f(u1.x);
    v.y += bf2f(u0.y) + bf2f(u1.y);
    v.z += bf2f(u0.z) + bf2f(u1.z);
    v.w += bf2f(u0.w) + bf2f(u1.w);
    ((float4*)x1)[i] = v;
    float s  = v.x + v.y + v.z + v.w;
    float sq = v.x*v.x + v.y*v.y + v.z*v.z + v.w*v.w;
#pragma unroll
    for (int m = 1; m < 64; m <<= 1) { s += __shfl_xor(s, m, 64); sq += __shfl_xor(sq, m, 64); }
    __shared__ float ls[4], lq[4];
    int wave = t >> 6, lane = t & 63;
    if (lane == 0) { ls[wave] = s; lq[wave] = sq; }
    __syncthreads();
    s  = ls[0]+ls[1]+ls[2]+ls[3];
    sq = lq[0]+lq[1]+lq[2]+lq[3];
    float mu  = s * (1.0f / D_MODEL);
    float var = sq * (1.0f / D_MODEL) - mu * mu;
    float rs  = rsqrtf(var + 1e-5f);
    int c = t * 4;
    float y0 = (v.x - mu) * rs * g[c+0] + b[c+0];
    float y1 = (v.y - mu) * rs * g[c+1] + b[c+1];
    float y2 = (v.z - mu) * rs * g[c+2] + b[c+2];
    float y3 = (v.w - mu) * rs * g[c+3] + b[c+3];
    unsigned* o = (unsigned*)(x2n + (size_t)row * D_MODEL + c);
    o[0] = pack2(y0, y1); o[1] = pack2(y2, y3);
}

// ---------------- final reduce: out = x1 + b_ff2 + sum(4 partials) ----------------
__global__ __launch_bounds__(256) void reduce_ff2(const float* __restrict__ res,
                                                  const float* __restrict__ bias,
                                                  const unsigned short* __restrict__ parts,
                                                  float* __restrict__ out) {
    int i = blockIdx.x * 256 + threadIdx.x;
    float4 r = ((const float4*)res)[i];
    float4 b = ((const float4*)bias)[i & (D_MODEL/4 - 1)];
    r.x += b.x; r.y += b.y; r.z += b.z; r.w += b.w;
#pragma unroll
    for (int p = 0; p < 4; p++) {
        ushort4 u = ((const ushort4*)(parts + (size_t)p * SEQ * D_MODEL))[i];
        r.x += bf2f(u.x); r.y += bf2f(u.y); r.z += bf2f(u.z); r.w += bf2f(u.w);
    }
    ((float4*)out)[i] = r;
}

// ---------------- GEMM core: TM=128 TN=64 BK=64, DMA dbuf, acc in caller regs ----------------
#define TMg 128
#define TNg 64
#define SMEM_U16 (2 * (TMg + TNg) * 64)   // 49152 B
__device__ __forceinline__ void gemm_core(const unsigned short* __restrict__ A,
                                          const unsigned short* __restrict__ Bt,
                                          int K, int K0, int KS, int bm, int bn,
                                          unsigned short* smem, f32x4 acc[4][2],
                                          int wave, int lane) {
    constexpr int AI = 4, BI = 2, MI = 4, NI = 2;
    constexpr int HALF = (TMg + TNg) * 64;
    int quad = lane >> 4, lr = lane & 15;

    const unsigned short* pa[AI];
    int aoff[AI];
#pragma unroll
    for (int i = 0; i < AI; i++) {
        int rl = wave*32 + i*8 + (lane >> 3);
        int ss = (lane & 7) ^ (rl & 7);
        pa[i] = A + (size_t)(bm*TMg + rl) * K + K0 + ss*8;
        aoff[i] = (wave*32 + i*8) * 64;
    }
    const unsigned short* pb[BI];
    int boff[BI];
#pragma unroll
    for (int i = 0; i < BI; i++) {
        int rl = wave*16 + i*8 + (lane >> 3);
        int ss = (lane & 7) ^ (rl & 7);
        pb[i] = Bt + (size_t)(bn*TNg + rl) * K + K0 + ss*8;
        boff[i] = TMg*64 + (wave*16 + i*8) * 64;
    }

    int wr = (wave >> 1) * 64, wc = (wave & 1) * 32;
    int foA[2][MI], foB[2][NI];
#pragma unroll
    for (int i = 0; i < MI; i++) {
        int row = wr + i*16 + lr;
        foA[0][i] = row*64 + ((quad     ^ (row & 7)))*8;
        foA[1][i] = row*64 + (((quad+4) ^ (row & 7)))*8;
    }
#pragma unroll
    for (int j = 0; j < NI; j++) {
        int row = wc + j*16 + lr;
        foB[0][j] = TMg*64 + row*64 + ((quad     ^ (row & 7)))*8;
        foB[1][j] = TMg*64 + row*64 + (((quad+4) ^ (row & 7)))*8;
    }

#pragma unroll
    for (int i = 0; i < AI; i++) gl_lds16(pa[i], smem + aoff[i]);
#pragma unroll
    for (int i = 0; i < BI; i++) gl_lds16(pb[i], smem + boff[i]);

    int bo = 0;
    for (int kk = 0; kk < KS; kk += 64) {
        __syncthreads();
        if (kk + 64 < KS) {
            int nb = bo ^ HALF;
#pragma unroll
            for (int i = 0; i < AI; i++) gl_lds16(pa[i] + kk + 64, smem + nb + aoff[i]);
#pragma unroll
            for (int i = 0; i < BI; i++) gl_lds16(pb[i] + kk + 64, smem + nb + boff[i]);
        }
#pragma unroll
        for (int h = 0; h < 2; h++) {
            bf16x8 af[MI], bfr[NI];
#pragma unroll
            for (int i = 0; i < MI; i++) af[i]  = ld_frag(smem + bo + foA[h][i]);
#pragma unroll
            for (int j = 0; j < NI; j++) bfr[j] = ld_frag(smem + bo + foB[h][j]);
#pragma unroll
            for (int i = 0; i < MI; i++)
#pragma unroll
                for (int j = 0; j < NI; j++)
                    acc[i][j] = MFMA16(af[i], bfr[j], acc[i][j]);
        }
        bo ^= HALF;
    }
}

__device__ __forceinline__ void acc_init(f32x4 acc[4][2]) {
    f32x4 z = {0.f, 0.f, 0.f, 0.f};
#pragma unroll
    for (int i = 0; i < 4; i++) { acc[i][0] = z; acc[i][1] = z; }
}

// ---------------- QKV GEMM + fused q/k-normalize + v-transpose epilogue ----------------
// bn in [0,48): sec = bn>>4 (0=q,1=k,2=v), h = bn&15. Block holds full head-dim (64 cols).
__global__ __launch_bounds__(256) void k_gemm_qkv(const unsigned short* __restrict__ A,
                                                  const unsigned short* __restrict__ Bt,
                                                  const float* __restrict__ bias,
                                                  unsigned short* __restrict__ qn,
                                                  unsigned short* __restrict__ kn,
                                                  unsigned short* __restrict__ vt) {
    __shared__ unsigned short smem[SMEM_U16];
    int t = threadIdx.x;
    int bn = blockIdx.x, bm = blockIdx.y;
    int wave = t >> 6, lane = t & 63;
    int quad = lane >> 4, lr = lane & 15;
    f32x4 acc[4][2];
    acc_init(acc);
    gemm_core(A, Bt, 1024, 0, 1024, bm, bn, smem, acc, wave, lane);

    int wr = (wave >> 1) * 64, wc = (wave & 1) * 32;
    int sec = bn >> 4, h = bn & 15;
    // add bias (b_qkv) before normalization
    float bv0 = bias[bn*64 + wc + lr];
    float bv1 = bias[bn*64 + wc + 16 + lr];
#pragma unroll
    for (int i = 0; i < 4; i++)
#pragma unroll
        for (int r = 0; r < 4; r++) { acc[i][0][r] += bv0; acc[i][1][r] += bv1; }

    if (sec < 2) {
        // row L2-norm over the 64-dim head: per-wave 32-col partial -> LDS -> combine
        float* sums = (float*)smem;        // [128][2] fp32 = 1KB (reuse staging LDS)
        __syncthreads();
#pragma unroll
        for (int i = 0; i < 4; i++)
#pragma unroll
            for (int r = 0; r < 4; r++) {
                float s = acc[i][0][r]*acc[i][0][r] + acc[i][1][r]*acc[i][1][r];
                s += __shfl_xor(s, 1, 64); s += __shfl_xor(s, 2, 64);
                s += __shfl_xor(s, 4, 64); s += __shfl_xor(s, 8, 64);
                if (lr == 0) sums[(wr + i*16 + quad*4 + r)*2 + (wave & 1)] = s;
            }
        __syncthreads();
        unsigned short* dst = (sec == 0) ? qn : kn;
        float mul = (sec == 0) ? 0.125f : 1.0f;   // fold 1/sqrt(HD) into q
#pragma unroll
        for (int i = 0; i < 4; i++)
#pragma unroll
            for (int r = 0; r < 4; r++) {
                int row = wr + i*16 + quad*4 + r;
                float tot = sums[row*2] + sums[row*2 + 1];
                float scale = mul / fmaxf(sqrtf(tot), 1e-12f);
                size_t base = ((size_t)h*SEQ + bm*128 + row) * HD;
                dst[base + wc + lr]      = f2bf(acc[i][0][r] * scale);
                dst[base + wc + 16 + lr] = f2bf(acc[i][1][r] * scale);
            }
    } else {
        // v: transpose 128l x 64d tile through LDS -> vt[h][d][l]
        __syncthreads();
        unsigned short (*lv)[130] = (unsigned short (*)[130])smem;  // 64 x 130 u16 = 16.6KB
#pragma unroll
        for (int i = 0; i < 4; i++)
#pragma unroll
            for (int j = 0; j < 2; j++)
#pragma unroll
                for (int r = 0; r < 4; r++)
                    lv[wc + j*16 + lr][wr + i*16 + quad*4 + r] = f2bf(acc[i][j][r]);
        __syncthreads();
        int d = t >> 2, l0 = (t & 3) * 32;
        unsigned short* ov = vt + ((size_t)(h*HD + d)) * SEQ + bm*128 + l0;
        ((uint4*)ov)[0] = *(uint4*)&lv[d][l0];
        ((uint4*)ov)[1] = *(uint4*)&lv[d][l0 + 8];
        ((uint4*)ov)[2] = *(uint4*)&lv[d][l0 + 16];
        ((uint4*)ov)[3] = *(uint4*)&lv[d][l0 + 24];
    }
}

// ---------------- split-K partial-output GEMMs (bf16 partial slices) ----------------
template<int SPLITK>
__device__ __forceinline__ void gemm_part(const unsigned short* A, const unsigned short* Bt,
                                          unsigned short* C, int M, int N, int K) {
    __shared__ unsigned short smem[SMEM_U16];
    int t = threadIdx.x;
    int bn = blockIdx.x, bm = blockIdx.y, kz = blockIdx.z;
    int wave = t >> 6, lane = t & 63;
    int quad = lane >> 4, lr = lane & 15;
    int KS = K / SPLITK;
    f32x4 acc[4][2];
    acc_init(acc);
    gemm_core(A, Bt, K, kz*KS, KS, bm, bn, smem, acc, wave, lane);
    int wr = (wave >> 1) * 64, wc = (wave & 1) * 32;
    unsigned short* P = C + (size_t)kz * M * N;
#pragma unroll
    for (int i = 0; i < 4; i++)
#pragma unroll
        for (int j = 0; j < 2; j++) {
            int row0 = bm*TMg + wr + i*16 + quad*4;
            int col  = bn*TNg + wc + j*16 + lr;
#pragma unroll
            for (int r = 0; r < 4; r++)
                P[(size_t)(row0 + r) * N + col] = f2bf(acc[i][j][r]);
        }
}
__global__ __launch_bounds__(256) void k_gemm_op(const unsigned short* A, const unsigned short* Bt,
                                                 unsigned short* C, int M, int N, int K) {
    gemm_part<2>(A, Bt, C, M, N, K);
}
__global__ __launch_bounds__(256) void k_gemm_ff2(const unsigned short* A, const unsigned short* Bt,
                                                  unsigned short* C, int M, int N, int K) {
    gemm_part<4>(A, Bt, C, M, N, K);
}

// ---------------- FF1 GEMM + bias + GELU -> bf16 ----------------
__global__ __launch_bounds__(256) void k_gemm_ff1(const unsigned short* __restrict__ A,
                                                  const unsigned short* __restrict__ Bt,
                                                  const float* __restrict__ bias,
                                                  unsigned short* __restrict__ C,
                                                  int M, int N, int K) {
    __shared__ unsigned short smem[SMEM_U16];
    int t = threadIdx.x;
    int bn = blockIdx.x, bm = blockIdx.y;
    int wave = t >> 6, lane = t & 63;
    int quad = lane >> 4, lr = lane & 15;
    f32x4 acc[4][2];
    acc_init(acc);
    gemm_core(A, Bt, K, 0, K, bm, bn, smem, acc, wave, lane);
    int wr = (wave >> 1) * 64, wc = (wave & 1) * 32;
#pragma unroll
    for (int i = 0; i < 4; i++)
#pragma unroll
        for (int j = 0; j < 2; j++) {
            int row0 = bm*TMg + wr + i*16 + quad*4;
            int col  = bn*TNg + wc + j*16 + lr;
            float bv = bias[col];
#pragma unroll
            for (int r = 0; r < 4; r++) {
                float v = acc[i][j][r] + bv;
                v = 0.5f * v * (1.0f + erff(v * 0.70710678118654752f));
                C[(size_t)(row0 + r) * N + col] = f2bf(v);
            }
        }
}

// ---------------- attention (proven): key-split KSPLIT=2, single-pass softmax ----------------
#define KSPLIT 2
#define KTILES (SEQ / 64 / KSPLIT)   // 16
__global__ __launch_bounds__(256) void attn_kernel(const unsigned short* __restrict__ qn,
                                                   const unsigned short* __restrict__ kn,
                                                   const unsigned short* __restrict__ vt,
                                                   const float* __restrict__ lcc,
                                                   float* __restrict__ num_ws,
                                                   float* __restrict__ den_ws) {
    __shared__ unsigned short lQ[64][72];
    __shared__ unsigned short lK[64][72];
    __shared__ unsigned short lV[64][72];   // [d][key]
    __shared__ unsigned short lP[64][72];   // [q_local][key]
    __shared__ float lL[SEQ / KSPLIT];
    int h = blockIdx.x, qb = blockIdx.y, kz = blockIdx.z;
    int t = threadIdx.x;
    int rl = t >> 2, c0 = (t & 3) << 4;
    const unsigned short* pq = qn + ((size_t)h*SEQ + qb*64 + rl)*HD + c0;
    *(uint4*)&lQ[rl][c0]     = ((const uint4*)pq)[0];
    *(uint4*)&lQ[rl][c0 + 8] = ((const uint4*)pq)[1];
    for (int i = t; i < SEQ/KSPLIT; i += 256) lL[i] = 0.05f * lcc[kz*(SEQ/KSPLIT) + i];
    __syncthreads();
    int wave = t >> 6, lane = t & 63, quad = lane >> 4, lr = lane & 15;
    float lqv[4];
#pragma unroll
    for (int r = 0; r < 4; r++) lqv[r] = 0.05f * lcc[qb*64 + wave*16 + quad*4 + r];
    bf16x8 aq0 = ld_frag(&lQ[wave*16 + lr][quad*8]);
    bf16x8 aq1 = ld_frag(&lQ[wave*16 + lr][32 + quad*8]);
    f32x4 z = {0.f, 0.f, 0.f, 0.f};
    f32x4 oacc[4]; oacc[0]=z; oacc[1]=z; oacc[2]=z; oacc[3]=z;
    float den[4] = {0.f, 0.f, 0.f, 0.f};

    const unsigned short* kn0 = kn + (size_t)h*SEQ*HD + (size_t)kz*(SEQ/KSPLIT)*HD;
    const unsigned short* vt0 = vt + (size_t)h*HD*SEQ + kz*(SEQ/KSPLIT);

    for (int kb = 0; kb < KTILES; kb++) {
        __syncthreads();
        const unsigned short* pk = kn0 + (size_t)(kb*64 + rl)*HD + c0;
        uint4 k0v = ((const uint4*)pk)[0], k1v = ((const uint4*)pk)[1];
        const unsigned short* pv = vt0 + (size_t)rl*SEQ + kb*64 + c0;
        uint4 v0v = ((const uint4*)pv)[0], v1v = ((const uint4*)pv)[1];
        *(uint4*)&lK[rl][c0]     = k0v; *(uint4*)&lK[rl][c0 + 8] = k1v;
        *(uint4*)&lV[rl][c0]     = v0v; *(uint4*)&lV[rl][c0 + 8] = v1v;
        __syncthreads();
#pragma unroll
        for (int j = 0; j < 4; j++) {
            bf16x8 b0 = ld_frag(&lK[j*16 + lr][quad*8]);
            bf16x8 b1 = ld_frag(&lK[j*16 + lr][32 + quad*8]);
            f32x4 s = z;
            s = MFMA16(aq0, b0, s);
            s = MFMA16(aq1, b1, s);
            float lm = lL[kb*64 + j*16 + lr];
#pragma unroll
            for (int r = 0; r < 4; r++) {
                float sv = s[r] + lqv[r] + lm;
                sv = fminf(fmaxf(sv, -10.f), 10.f);
                float p = __expf(sv);
                den[r] += p;
                lP[wave*16 + quad*4 + r][j*16 + lr] = f2bf(p);
            }
        }
        bf16x8 ap0 = ld_frag(&lP[wave*16 + lr][quad*8]);
        bf16x8 ap1 = ld_frag(&lP[wave*16 + lr][32 + quad*8]);
#pragma unroll
        for (int j2 = 0; j2 < 4; j2++) {
            bf16x8 b0 = ld_frag(&lV[j2*16 + lr][quad*8]);
            bf16x8 b1 = ld_frag(&lV[j2*16 + lr][32 + quad*8]);
            oacc[j2] = MFMA16(ap0, b0, oacc[j2]);
            oacc[j2] = MFMA16(ap1, b1, oacc[j2]);
        }
    }
#pragma unroll
    for (int r = 0; r < 4; r++)
#pragma unroll
        for (int m = 1; m < 16; m <<= 1) den[r] += __shfl_xor(den[r], m, 64);

    float* nump = num_ws + (((size_t)(h*32 + qb)) * KSPLIT + kz) * 4096;
#pragma unroll
    for (int j2 = 0; j2 < 4; j2++)
#pragma unroll
        for (int r = 0; r < 4; r++)
            nump[(wave*16 + quad*4 + r) * 64 + j2*16 + lr] = oacc[j2][r];
    if (lr == 0) {
        float* denp = den_ws + (((size_t)(h*32 + qb)) * KSPLIT + kz) * 64;
#pragma unroll
        for (int r = 0; r < 4; r++) denp[wave*16 + quad*4 + r] = den[r];
    }
}

// combine: out[qb*64+row][h*64+col] = sum_kz num / sum_kz den
__global__ __launch_bounds__(256) void attn_comb(const float* __restrict__ num_ws,
                                                 const float* __restrict__ den_ws,
                                                 unsigned short* __restrict__ attn) {
    int hq = blockIdx.x;          // h*32+qb
    int h = hq >> 5, qb = hq & 31;
    int t = threadIdx.x;
    int row = t >> 2, col0 = (t & 3) << 4;
    const float* n0 = num_ws + ((size_t)hq * KSPLIT) * 4096 + row*64 + col0;
    const float* n1 = n0 + 4096;
    float d = den_ws[(size_t)hq * KSPLIT * 64 + row] + den_ws[((size_t)hq * KSPLIT + 1) * 64 + row];
    float inv = 1.0f / d;
    unsigned ob[8];
#pragma unroll
    for (int i = 0; i < 4; i++) {
        float4 a = ((const float4*)n0)[i];
        float4 b = ((const float4*)n1)[i];
        ob[2*i]   = pack2((a.x + b.x) * inv, (a.y + b.y) * inv);
        ob[2*i+1] = pack2((a.z + b.z) * inv, (a.w + b.w) * inv);
    }
    unsigned short* op = attn + (size_t)(qb*64 + row) * D_MODEL + h*64 + col0;
    ((uint4*)op)[0] = *(uint4*)&ob[0];
    ((uint4*)op)[1] = *(uint4*)&ob[4];
}

// ---------------- host orchestration ----------------
extern "C" void kernel_launch(void* const* d_in, const int* in_sizes, int n_in,
                              void* d_out, int out_size, void* d_ws, size_t ws_size,
                              hipStream_t stream) {
    const float* x      = (const float*)d_in[0];
    const float* lcc    = (const float*)d_in[1];
    const float* w_qkv  = (const float*)d_in[2];
    const float* b_qkv  = (const float*)d_in[3];
    const float* w_out  = (const float*)d_in[4];
    const float* b_out  = (const float*)d_in[5];
    const float* ln1_g  = (const float*)d_in[6];
    const float* ln1_b  = (const float*)d_in[7];
    const float* ln2_g  = (const float*)d_in[8];
    const float* ln2_b  = (const float*)d_in[9];
    const float* w_ff1  = (const float*)d_in[10];
    const float* b_ff1  = (const float*)d_in[11];
    const float* w_ff2  = (const float*)d_in[12];
    const float* b_ff2  = (const float*)d_in[13];

    char* ws = (char*)d_ws;
    unsigned short* wtq  = (unsigned short*)(ws);                    // -> 6291456
    unsigned short* wto  = (unsigned short*)(ws + 6291456);          // -> 8388608
    unsigned short* wtf1 = (unsigned short*)(ws + 8388608);          // -> 16777216
    unsigned short* wtf2 = (unsigned short*)(ws + 16777216);         // -> 25165824
    unsigned short* xn   = (unsigned short*)(ws + 25165824);         // -> 29360128
    float*          x1   = (float*)(ws + 29360128);                  // 2048x1024 f32 -> 37748736
    float*          numw = (float*)(ws + 29360128);                  // alias: attn num partials (16.8MB)
    float*          denw = (float*)(ws + 46137344);                  // 256KB attn den partials
    unsigned short* hbuf = (unsigned short*)(ws + 37748736);         // 2048x4096 bf16 -> 54525952
    unsigned short* pOP  = (unsigned short*)(ws + 37748736);         // alias: 2 bf16 slices
    unsigned short* qnb  = (unsigned short*)(ws + 54525952);         // -> 58720256
    unsigned short* knb  = (unsigned short*)(ws + 58720256);         // -> 62914560
    unsigned short* vtb  = (unsigned short*)(ws + 62914560);         // -> 67108864
    unsigned short* pFF2 = (unsigned short*)(ws);                    // alias (weights dead): exactly 16777216B
    unsigned short* attnb = xn;                                      // alias (xn dead after QKV gemm)
    unsigned short* x2n  = qnb;                                      // alias (qn dead after attention)
    float* outp = (float*)d_out;

    // Ordering (sequential stream): numw aliases x1 region — attn partials consumed by
    // attn_comb before reduce_ln writes x1. pOP overlaps numw tail — OP gemm after attn_comb.
    // pFF2 overwrites wtq/wto/wtf1 (dead), ends exactly at wtf2 (still live for FF2 reads).

    wcast_all<<<3072, 256, 0, stream>>>(w_qkv, w_out, w_ff1, w_ff2, wtq, wto, wtf1, wtf2);
    ln_kernel<<<SEQ, 256, 0, stream>>>(x, ln1_g, ln1_b, xn);
    k_gemm_qkv<<<dim3(48, 16), 256, 0, stream>>>(xn, wtq, b_qkv, qnb, knb, vtb);
    attn_kernel<<<dim3(16, 32, KSPLIT), 256, 0, stream>>>(qnb, knb, vtb, lcc, numw, denw);
    attn_comb<<<512, 256, 0, stream>>>(numw, denw, attnb);
    k_gemm_op<<<dim3(16, 16, 2), 256, 0, stream>>>(attnb, wto, pOP, SEQ, 1024, 1024);
    reduce_ln<<<SEQ, 256, 0, stream>>>(x, b_out, pOP, ln2_g, ln2_b, x1, x2n);
    k_gemm_ff1<<<dim3(64, 16), 256, 0, stream>>>(x2n, wtf1, b_ff1, hbuf, SEQ, 4096, 1024);
    k_gemm_ff2<<<dim3(16, 16, 4), 256, 0, stream>>>(hbuf, wtf2, pFF2, SEQ, 1024, 4096);
    reduce_ff2<<<SEQ*D_MODEL/1024, 256, 0, stream>>>(x1, b_ff2, pFF2, outp);
}